// Round 12
// baseline (118.914 us; speedup 1.0000x reference)
//
#include <hip/hip_runtime.h>
#include <hip/hip_fp16.h>

// FourierFilter: out = Re(IFFT(mask * FFT(x, axis=-1))), mask zeroes bins with
// |freq| < 10 Hz (kf <= 819 of 8192 @ 100 Hz). x: [64,128,8192] f32.
//
// Register-resident four-step FFT, two real rows packed per complex row.
// 256 threads x 32 complex regs. Stage grouping 3+5+5: phase-1 chains
// {4t+e+1024m} (float4 global I/O), phase-2 chains {1024(t>>5)+(t&31)+32m},
// phase-3 contiguous {32t+e} with fwd FFT-32 + MASK(brev13) + inv FFT-32
// fused in registers. Inverse mirrors (conj pre-twiddle, DIT).
// 4 LDS RTs / 5 barriers per pair. LDS fp16 __half2, pad i+(i>>6) (33,280 B,
// 4 blocks/CU). Loads cached; stores nontemporal. cmul = inline-asm VOP3P
// (v_pk_mul_f32 + v_pk_fma_f32 with op_sel/neg_lo = 2-op complex multiply).
//
// R11 change: persistent blocks + register prefetch. Grid=1024 (4 blocks/CU
// exactly), each block processes npairs/1024 = 4 pairs. Next pair's input is
// loaded into pf[] registers at the TOP of the current iteration, so HBM
// latency hides under the full ~25us of FFT compute instead of stalling P1.
// +64 VGPR for pf is free: occupancy is LDS-bound (4 blocks/CU), 512
// VGPR/wave available at 4 waves/SIMD.
// R9 lesson: 5 blocks/CU via 32KB-exact LDS regressed — stay at 4.
// R6 lesson: shuffle-based stages regressed (VALUBusy 66%) — stay LDS-based.

#define FFT_N 8192
#define NT    256
#define GRID  1024
#define PHY(i) ((i) + ((i) >> 6))

typedef float v2f __attribute__((ext_vector_type(2)));
typedef float v4f __attribute__((ext_vector_type(4)));

__device__ __forceinline__ v2f cmul(v2f a, v2f b){
  v2f t, d;
  asm("v_pk_mul_f32 %0, %1, %2 op_sel:[0,0] op_sel_hi:[0,1]"
      : "=&v"(t) : "v"(a), "v"(b));
  asm("v_pk_fma_f32 %0, %1, %2, %3 op_sel:[1,1,0] op_sel_hi:[1,0,1] neg_lo:[0,1,0]"
      : "=v"(d) : "v"(a), "v"(b), "v"(t));
  return d;
}

// d * W_32^j (or conj), j in [0,16), compile-time after unroll -> constants fold.
__device__ __forceinline__ v2f mul_w32(v2f d, int j, bool cj){
  if (j == 0) return d;
  if (j == 8) return cj ? (v2f){-d.y, d.x} : (v2f){d.y, -d.x};
  const float C[16] = {1.f, 0.98078528f, 0.92387953f, 0.83146961f, 0.70710678f,
                       0.55557023f, 0.38268343f, 0.19509032f, 0.f, -0.19509032f,
                       -0.38268343f, -0.55557023f, -0.70710678f, -0.83146961f,
                       -0.92387953f, -0.98078528f};
  const float S[16] = {0.f, -0.19509032f, -0.38268343f, -0.55557023f, -0.70710678f,
                       -0.83146961f, -0.92387953f, -0.98078528f, -1.f, -0.98078528f,
                       -0.92387953f, -0.83146961f, -0.70710678f, -0.55557023f,
                       -0.38268343f, -0.19509032f};
  v2f w = {C[j], cj ? -S[j] : S[j]};
  return cmul(d, w);
}

// DIF radix-2 stages, spans L..1 over SZ regs. Stage twiddle W_{2L}^j == W_32^{j*16/L}.
template<int SZ, int L>
__device__ __forceinline__ void dif_rec(v2f* r){
  #pragma unroll
  for (int g = 0; g < SZ; g += 2*L){
    #pragma unroll
    for (int j = 0; j < L; ++j){
      v2f u = r[g+j], v = r[g+j+L];
      r[g+j]   = u + v;
      r[g+j+L] = mul_w32(u - v, j*(16/L), false);
    }
  }
  if constexpr (L > 1) dif_rec<SZ, L/2>(r);
}

// Inverse DIT radix-2 stages, spans 1..SZ/2 (conjugate twiddles), unnormalized.
template<int SZ, int L>
__device__ __forceinline__ void dit_rec(v2f* r){
  #pragma unroll
  for (int g = 0; g < SZ; g += 2*L){
    #pragma unroll
    for (int j = 0; j < L; ++j){
      v2f a = r[g+j];
      v2f b = mul_w32(r[g+j+L], j*(16/L), true);
      r[g+j]   = a + b;
      r[g+j+L] = a - b;
    }
  }
  if constexpr (2*L < SZ) dit_rec<SZ, 2*L>(r);
}

__host__ __device__ constexpr int brev5(int k){
  return ((k&1)<<4) | ((k&2)<<2) | (k&4) | ((k&8)>>2) | ((k&16)>>4);
}

// r[brev5(k)] *= W_8192^{cbase*k} (or conj), k=1..31 (two half-chains for ILP).
__device__ __forceinline__ void twiddle_scale(v2f* r, int cbase, bool cj){
  float s, c;
  __sincosf((float)cbase * -7.6699039394282061e-4f, &s, &c);  // -2*pi/8192
  if (cj) s = -s;
  const v2f w1 = {c, s};
  v2f w2q = cmul(w1, w1);
  v2f w4q = cmul(w2q, w2q);
  v2f w8q = cmul(w4q, w4q);
  v2f w16 = cmul(w8q, w8q);
  v2f wa = w1;
  r[brev5(1)]  = cmul(r[brev5(1)],  wa);
  r[brev5(17)] = cmul(r[brev5(17)], cmul(w16, wa));
  #pragma unroll
  for (int k = 2; k <= 15; ++k){
    wa = cmul(wa, w1);
    r[brev5(k)]    = cmul(r[brev5(k)],    wa);
    r[brev5(k+16)] = cmul(r[brev5(k+16)], cmul(w16, wa));
  }
  r[brev5(16)] = cmul(r[brev5(16)], w16);
}

// r[brev3(k)] *= w1^k, k=1..7, w1 = W_8192^c (pass conj(w1) for inverse).
// brev3: 1->4, 2->2, 3->6, 4->1, 5->5, 6->3, 7->7.
__device__ __forceinline__ void tw8(v2f* r, v2f w1){
  v2f w2 = cmul(w1, w1);
  v2f w3 = cmul(w2, w1);
  v2f w4 = cmul(w2, w2);
  v2f w5 = cmul(w4, w1);
  v2f w6 = cmul(w4, w2);
  v2f w7 = cmul(w4, w3);
  r[4] = cmul(r[4], w1);
  r[2] = cmul(r[2], w2);
  r[6] = cmul(r[6], w3);
  r[1] = cmul(r[1], w4);
  r[5] = cmul(r[5], w5);
  r[3] = cmul(r[3], w6);
  r[7] = cmul(r[7], w7);
}

__global__ __launch_bounds__(NT, 2)
void fourier_filter_kernel(const float* __restrict__ x, float* __restrict__ out,
                           int npairs){
  __shared__ __half2 zs[FFT_N + FFT_N/64];   // 8320 * 4B = 32.5 KB (pad every 64)
  const int t = threadIdx.x;

  // W_8192^1, W_8192^2 (for chain bases 4t+1, 4t+2, 4t+3)
  const v2f W1C = {0.9999997058629f, -7.669903187e-4f};
  const v2f W2C = {0.9999988234517f, -1.5339801863e-3f};

  v4f pfa[8], pfb[8];                        // prefetch regs for next pair
  long long pair = blockIdx.x;
  {
    const float* q0 = x + pair * (2LL * FFT_N);
    const float* q1 = q0 + FFT_N;
    #pragma unroll
    for (int m = 0; m < 8; ++m){
      const int n = 4*t + (m << 10);
      pfa[m] = *reinterpret_cast<const v4f*>(q0 + n);
      pfb[m] = *reinterpret_cast<const v4f*>(q1 + n);
    }
  }

  #pragma unroll 1
  for (; pair < npairs; pair += GRID){
    v2f r[32];

    // ---- unpack prefetched input (waits on loads), then issue next prefetch ----
    #pragma unroll
    for (int m = 0; m < 8; ++m){
      r[0*8+m] = (v2f){pfa[m].x, pfb[m].x};
      r[1*8+m] = (v2f){pfa[m].y, pfb[m].y};
      r[2*8+m] = (v2f){pfa[m].z, pfb[m].z};
      r[3*8+m] = (v2f){pfa[m].w, pfb[m].w};
    }
    if (pair + GRID < npairs){
      const float* q0 = x + (pair + GRID) * (2LL * FFT_N);
      const float* q1 = q0 + FFT_N;
      #pragma unroll
      for (int m = 0; m < 8; ++m){
        const int n = 4*t + (m << 10);
        pfa[m] = *reinterpret_cast<const v4f*>(q0 + n);
        pfb[m] = *reinterpret_cast<const v4f*>(q1 + n);
      }
    }

    // ---- fwd phase 1: 4 chains c=4t+e, FFT-8 over m (n = 4t+e+1024m) ----
    #pragma unroll
    for (int e = 0; e < 4; ++e) dif_rec<8, 4>(r + 8*e);
    {
      float s, c;
      __sincosf((float)(4*t) * -7.6699039394282061e-4f, &s, &c);
      v2f w0 = {c, s};
      v2f wA = cmul(w0, W1C);
      v2f wB = cmul(w0, W2C);
      v2f wC = cmul(wA, W2C);
      tw8(r + 0,  w0);
      tw8(r + 8,  wA);
      tw8(r + 16, wB);
      tw8(r + 24, wC);
    }
    #pragma unroll
    for (int e = 0; e < 4; ++e)
      #pragma unroll
      for (int m = 0; m < 8; ++m)
        zs[PHY(4*t + e + (m<<10))] = __floats2half2_rn(r[8*e+m].x, r[8*e+m].y);
    __syncthreads();

    // ---- fwd phase 2: chains {1024(t>>5) + (t&31) + 32m}, FFT-32 ----
    const int base2 = ((t >> 5) << 10) | (t & 31);
    #pragma unroll
    for (int m = 0; m < 32; ++m){
      float2 f = __half22float2(zs[PHY(base2 + (m<<5))]);
      r[m] = (v2f){f.x, f.y};
    }
    dif_rec<32, 16>(r);
    twiddle_scale(r, (t & 31) << 3, false);  // W_1024^{c2*k} = W_8192^{8*c2*k}
    #pragma unroll
    for (int m = 0; m < 32; ++m)
      zs[PHY(base2 + (m<<5))] = __floats2half2_rn(r[m].x, r[m].y);
    __syncthreads();

    // ---- phase 3: contiguous FFT-32 fwd + MASK + inv, fused in regs ----
    #pragma unroll
    for (int e = 0; e < 32; ++e){
      float2 f = __half22float2(zs[PHY((t<<5) + e)]);
      r[e] = (v2f){f.x, f.y};
    }
    dif_rec<32, 16>(r);
    #pragma unroll
    for (int e = 0; e < 32; ++e){
      const int v  = (t << 5) + e;
      const int k  = (int)(__brev((unsigned)v) >> 19);  // slot v holds bin brev13(v)
      const int kf = min(k, FFT_N - k);
      if (kf <= 819) r[e] = (v2f){0.f, 0.f};            // |freq| < 10 Hz
    }
    dit_rec<32, 1>(r);
    #pragma unroll
    for (int e = 0; e < 32; ++e)
      zs[PHY((t<<5) + e)] = __floats2half2_rn(r[e].x, r[e].y);
    __syncthreads();

    // ---- inv phase 2: conj pre-twiddle, DIT ----
    #pragma unroll
    for (int m = 0; m < 32; ++m){
      float2 f = __half22float2(zs[PHY(base2 + (m<<5))]);
      r[m] = (v2f){f.x, f.y};
    }
    twiddle_scale(r, (t & 31) << 3, true);
    dit_rec<32, 1>(r);
    #pragma unroll
    for (int m = 0; m < 32; ++m)
      zs[PHY(base2 + (m<<5))] = __floats2half2_rn(r[m].x, r[m].y);
    __syncthreads();

    // ---- inv phase 1: conj pre-twiddle, 4 x DIT-8, vec4 store ----
    #pragma unroll
    for (int e = 0; e < 4; ++e)
      #pragma unroll
      for (int m = 0; m < 8; ++m){
        float2 f = __half22float2(zs[PHY(4*t + e + (m<<10))]);
        r[8*e+m] = (v2f){f.x, f.y};
      }
    {
      float s, c;
      __sincosf((float)(4*t) * -7.6699039394282061e-4f, &s, &c);
      v2f w0 = {c, -s};                      // conj(W^{4t})
      const v2f W1Cc = {W1C.x, -W1C.y};
      const v2f W2Cc = {W2C.x, -W2C.y};
      v2f wA = cmul(w0, W1Cc);
      v2f wB = cmul(w0, W2Cc);
      v2f wC = cmul(wA, W2Cc);
      tw8(r + 0,  w0);
      tw8(r + 8,  wA);
      tw8(r + 16, wB);
      tw8(r + 24, wC);
    }
    #pragma unroll
    for (int e = 0; e < 4; ++e) dit_rec<8, 1>(r + 8*e);

    const float invn = 1.f / (float)FFT_N;
    float* o0 = out + pair * (2LL * FFT_N);
    float* o1 = o0 + FFT_N;
    #pragma unroll
    for (int m = 0; m < 8; ++m){
      const int n = 4*t + (m << 10);
      v4f a, b;
      a.x = r[0*8+m].x * invn;  b.x = r[0*8+m].y * invn;
      a.y = r[1*8+m].x * invn;  b.y = r[1*8+m].y * invn;
      a.z = r[2*8+m].x * invn;  b.z = r[2*8+m].y * invn;
      a.w = r[3*8+m].x * invn;  b.w = r[3*8+m].y * invn;
      __builtin_nontemporal_store(a, reinterpret_cast<v4f*>(o0 + n));
      __builtin_nontemporal_store(b, reinterpret_cast<v4f*>(o1 + n));
    }
    __syncthreads();   // protect LDS before next iteration's phase-1 writes
  }
}

extern "C" void kernel_launch(void* const* d_in, const int* in_sizes, int n_in,
                              void* d_out, int out_size, void* d_ws, size_t ws_size,
                              hipStream_t stream) {
  const float* x = (const float*)d_in[0];
  float* out = (float*)d_out;
  const int total  = in_sizes[0];              // 64*128*8192
  const int npairs = total / (2 * FFT_N);      // 4096 row pairs
  const int grid   = npairs < GRID ? npairs : GRID;
  hipLaunchKernelGGL(fourier_filter_kernel, dim3(grid), dim3(NT), 0, stream,
                     x, out, npairs);
}

// Round 14
// 103.458 us; speedup vs baseline: 1.1494x; 1.1494x over previous
//
#include <hip/hip_runtime.h>
#include <hip/hip_fp16.h>

// FourierFilter: out = Re(IFFT(mask * FFT(x, axis=-1))), mask zeroes bins with
// |freq| < 10 Hz (kf <= 819 of 8192 @ 100 Hz). x: [64,128,8192] f32.
//
// Register-resident four-step FFT, two real rows packed per complex row.
// 256 threads x 32 complex regs. Stage grouping 3+5+5: phase-1 chains
// {4t+e+1024m} (float4 global I/O), phase-2 chains {1024(t>>5)+(t&31)+32m},
// phase-3 contiguous {32t+e} fwd FFT-32 + MASK(brev13) + inv FFT-32 fused.
// Inverse mirrors (conj pre-twiddle, DIT). 4 LDS RTs / 4 barriers.
// cmul = inline-asm VOP3P packed (v_pk_mul_f32 + v_pk_fma_f32, 2 ops).
//
// R13 = R10 base + LDS b128 widening ONLY (single-variable):
//   pad granularity 4 elems: PHY4(i) = i + ((i>>6)<<2) keeps 4 consecutive
//   slots contiguous + 16B aligned -> P1w/P3r/P3w/iP1r are ds_*_b128
//   (LDS instrs 256 -> 160/thread). P2/iP2 stay scalar (stride-32 pattern).
//   LDS = 8704 * 4B = 34,816 B -> still 4 blocks/CU.
// LEDGER: R12 barrier elision (wave-local fences for P2->P3->iP2) FAILED
//   correctness (absmax 4.7) despite plane math checking out — mechanism
//   unexplained, reverted, do not retry without disasm evidence.
// R11: persistent+prefetch lost to HW inter-block overlap (occ 27->18.5).
// R9: forcing 5 blocks/CU regressed. R6: shuffle stages regressed.

#define FFT_N 8192
#define NT    256
#define PHY4(i) ((i) + (((i) >> 6) << 2))

typedef float v2f __attribute__((ext_vector_type(2)));
typedef float v4f __attribute__((ext_vector_type(4)));

union H2x4 { __half2 h[4]; v4f v; };

__device__ __forceinline__ v2f cmul(v2f a, v2f b){
  v2f t, d;
  asm("v_pk_mul_f32 %0, %1, %2 op_sel:[0,0] op_sel_hi:[0,1]"
      : "=&v"(t) : "v"(a), "v"(b));
  asm("v_pk_fma_f32 %0, %1, %2, %3 op_sel:[1,1,0] op_sel_hi:[1,0,1] neg_lo:[0,1,0]"
      : "=v"(d) : "v"(a), "v"(b), "v"(t));
  return d;
}

// d * W_32^j (or conj), j in [0,16), compile-time after unroll -> constants fold.
__device__ __forceinline__ v2f mul_w32(v2f d, int j, bool cj){
  if (j == 0) return d;
  if (j == 8) return cj ? (v2f){-d.y, d.x} : (v2f){d.y, -d.x};
  const float C[16] = {1.f, 0.98078528f, 0.92387953f, 0.83146961f, 0.70710678f,
                       0.55557023f, 0.38268343f, 0.19509032f, 0.f, -0.19509032f,
                       -0.38268343f, -0.55557023f, -0.70710678f, -0.83146961f,
                       -0.92387953f, -0.98078528f};
  const float S[16] = {0.f, -0.19509032f, -0.38268343f, -0.55557023f, -0.70710678f,
                       -0.83146961f, -0.92387953f, -0.98078528f, -1.f, -0.98078528f,
                       -0.92387953f, -0.83146961f, -0.70710678f, -0.55557023f,
                       -0.38268343f, -0.19509032f};
  v2f w = {C[j], cj ? -S[j] : S[j]};
  return cmul(d, w);
}

// DIF radix-2 stages, spans L..1 over SZ regs. Stage twiddle W_{2L}^j == W_32^{j*16/L}.
template<int SZ, int L>
__device__ __forceinline__ void dif_rec(v2f* r){
  #pragma unroll
  for (int g = 0; g < SZ; g += 2*L){
    #pragma unroll
    for (int j = 0; j < L; ++j){
      v2f u = r[g+j], v = r[g+j+L];
      r[g+j]   = u + v;
      r[g+j+L] = mul_w32(u - v, j*(16/L), false);
    }
  }
  if constexpr (L > 1) dif_rec<SZ, L/2>(r);
}

// Inverse DIT radix-2 stages, spans 1..SZ/2 (conjugate twiddles), unnormalized.
template<int SZ, int L>
__device__ __forceinline__ void dit_rec(v2f* r){
  #pragma unroll
  for (int g = 0; g < SZ; g += 2*L){
    #pragma unroll
    for (int j = 0; j < L; ++j){
      v2f a = r[g+j];
      v2f b = mul_w32(r[g+j+L], j*(16/L), true);
      r[g+j]   = a + b;
      r[g+j+L] = a - b;
    }
  }
  if constexpr (2*L < SZ) dit_rec<SZ, 2*L>(r);
}

__host__ __device__ constexpr int brev5(int k){
  return ((k&1)<<4) | ((k&2)<<2) | (k&4) | ((k&8)>>2) | ((k&16)>>4);
}

// r[brev5(k)] *= W_8192^{cbase*k} (or conj), k=1..31 (two half-chains for ILP).
__device__ __forceinline__ void twiddle_scale(v2f* r, int cbase, bool cj){
  float s, c;
  __sincosf((float)cbase * -7.6699039394282061e-4f, &s, &c);  // -2*pi/8192
  if (cj) s = -s;
  const v2f w1 = {c, s};
  v2f w2q = cmul(w1, w1);
  v2f w4q = cmul(w2q, w2q);
  v2f w8q = cmul(w4q, w4q);
  v2f w16 = cmul(w8q, w8q);
  v2f wa = w1;
  r[brev5(1)]  = cmul(r[brev5(1)],  wa);
  r[brev5(17)] = cmul(r[brev5(17)], cmul(w16, wa));
  #pragma unroll
  for (int k = 2; k <= 15; ++k){
    wa = cmul(wa, w1);
    r[brev5(k)]    = cmul(r[brev5(k)],    wa);
    r[brev5(k+16)] = cmul(r[brev5(k+16)], cmul(w16, wa));
  }
  r[brev5(16)] = cmul(r[brev5(16)], w16);
}

// r[brev3(k)] *= w1^k, k=1..7, w1 = W_8192^c (pass conj(w1) for inverse).
// brev3: 1->4, 2->2, 3->6, 4->1, 5->5, 6->3, 7->7.
__device__ __forceinline__ void tw8(v2f* r, v2f w1){
  v2f w2 = cmul(w1, w1);
  v2f w3 = cmul(w2, w1);
  v2f w4 = cmul(w2, w2);
  v2f w5 = cmul(w4, w1);
  v2f w6 = cmul(w4, w2);
  v2f w7 = cmul(w4, w3);
  r[4] = cmul(r[4], w1);
  r[2] = cmul(r[2], w2);
  r[6] = cmul(r[6], w3);
  r[1] = cmul(r[1], w4);
  r[5] = cmul(r[5], w5);
  r[3] = cmul(r[3], w6);
  r[7] = cmul(r[7], w7);
}

__global__ __launch_bounds__(NT, 2)
void fourier_filter_kernel(const float* __restrict__ x, float* __restrict__ out){
  __shared__ __half2 zs[FFT_N + (FFT_N/64)*4];   // 8704 * 4B = 34,816 B
  const int t = threadIdx.x;
  const long long pair = blockIdx.x;
  const float* r0 = x + pair * (2LL * FFT_N);
  const float* r1 = r0 + FFT_N;
  v2f r[32];

  // W_8192^1, W_8192^2 (for chain bases 4t+1, 4t+2, 4t+3)
  const v2f W1C = {0.9999997058629f, -7.669903187e-4f};
  const v2f W2C = {0.9999988234517f, -1.5339801863e-3f};

  // ---- fwd phase 1: 4 chains c=4t+e, FFT-8 over m (n = 4t+e+1024m) ----
  #pragma unroll
  for (int m = 0; m < 8; ++m){
    const int n = 4*t + (m << 10);
    const v4f a = *reinterpret_cast<const v4f*>(r0 + n);
    const v4f b = *reinterpret_cast<const v4f*>(r1 + n);
    r[0*8+m] = (v2f){a.x, b.x};
    r[1*8+m] = (v2f){a.y, b.y};
    r[2*8+m] = (v2f){a.z, b.z};
    r[3*8+m] = (v2f){a.w, b.w};
  }
  #pragma unroll
  for (int e = 0; e < 4; ++e) dif_rec<8, 4>(r + 8*e);
  {
    float s, c;
    __sincosf((float)(4*t) * -7.6699039394282061e-4f, &s, &c);
    v2f w0 = {c, s};
    v2f wA = cmul(w0, W1C);
    v2f wB = cmul(w0, W2C);
    v2f wC = cmul(wA, W2C);
    tw8(r + 0,  w0);
    tw8(r + 8,  wA);
    tw8(r + 16, wB);
    tw8(r + 24, wC);
  }
  #pragma unroll
  for (int m = 0; m < 8; ++m){
    H2x4 u;
    #pragma unroll
    for (int e = 0; e < 4; ++e)
      u.h[e] = __floats2half2_rn(r[8*e+m].x, r[8*e+m].y);
    *reinterpret_cast<v4f*>(&zs[PHY4(4*t + (m<<10))]) = u.v;   // ds_write_b128
  }
  __syncthreads();

  // ---- fwd phase 2: chains {1024(t>>5) + (t&31) + 32m}, FFT-32 ----
  const int base2 = ((t >> 5) << 10) | (t & 31);
  #pragma unroll
  for (int m = 0; m < 32; ++m){
    float2 f = __half22float2(zs[PHY4(base2 + (m<<5))]);
    r[m] = (v2f){f.x, f.y};
  }
  dif_rec<32, 16>(r);
  twiddle_scale(r, (t & 31) << 3, false);   // W_1024^{c2*k} = W_8192^{8*c2*k}
  #pragma unroll
  for (int m = 0; m < 32; ++m)
    zs[PHY4(base2 + (m<<5))] = __floats2half2_rn(r[m].x, r[m].y);
  __syncthreads();

  // ---- phase 3: contiguous FFT-32 fwd + MASK + inv, fused in regs ----
  #pragma unroll
  for (int q = 0; q < 8; ++q){
    H2x4 u;
    u.v = *reinterpret_cast<const v4f*>(&zs[PHY4((t<<5) + 4*q)]);  // ds_read_b128
    #pragma unroll
    for (int j = 0; j < 4; ++j){
      float2 f = __half22float2(u.h[j]);
      r[4*q+j] = (v2f){f.x, f.y};
    }
  }
  dif_rec<32, 16>(r);
  #pragma unroll
  for (int e = 0; e < 32; ++e){
    const int v  = (t << 5) + e;
    const int k  = (int)(__brev((unsigned)v) >> 19);   // slot v holds bin brev13(v)
    const int kf = min(k, FFT_N - k);
    if (kf <= 819) r[e] = (v2f){0.f, 0.f};             // |freq| < 10 Hz
  }
  dit_rec<32, 1>(r);
  #pragma unroll
  for (int q = 0; q < 8; ++q){
    H2x4 u;
    #pragma unroll
    for (int j = 0; j < 4; ++j)
      u.h[j] = __floats2half2_rn(r[4*q+j].x, r[4*q+j].y);
    *reinterpret_cast<v4f*>(&zs[PHY4((t<<5) + 4*q)]) = u.v;      // ds_write_b128
  }
  __syncthreads();

  // ---- inv phase 2: conj pre-twiddle, DIT ----
  #pragma unroll
  for (int m = 0; m < 32; ++m){
    float2 f = __half22float2(zs[PHY4(base2 + (m<<5))]);
    r[m] = (v2f){f.x, f.y};
  }
  twiddle_scale(r, (t & 31) << 3, true);
  dit_rec<32, 1>(r);
  #pragma unroll
  for (int m = 0; m < 32; ++m)
    zs[PHY4(base2 + (m<<5))] = __floats2half2_rn(r[m].x, r[m].y);
  __syncthreads();

  // ---- inv phase 1: conj pre-twiddle, 4 x DIT-8, vec4 store ----
  #pragma unroll
  for (int m = 0; m < 8; ++m){
    H2x4 u;
    u.v = *reinterpret_cast<const v4f*>(&zs[PHY4(4*t + (m<<10))]);  // ds_read_b128
    #pragma unroll
    for (int e = 0; e < 4; ++e){
      float2 f = __half22float2(u.h[e]);
      r[8*e+m] = (v2f){f.x, f.y};
    }
  }
  {
    float s, c;
    __sincosf((float)(4*t) * -7.6699039394282061e-4f, &s, &c);
    v2f w0 = {c, -s};                        // conj(W^{4t})
    const v2f W1Cc = {W1C.x, -W1C.y};
    const v2f W2Cc = {W2C.x, -W2C.y};
    v2f wA = cmul(w0, W1Cc);
    v2f wB = cmul(w0, W2Cc);
    v2f wC = cmul(wA, W2Cc);
    tw8(r + 0,  w0);
    tw8(r + 8,  wA);
    tw8(r + 16, wB);
    tw8(r + 24, wC);
  }
  #pragma unroll
  for (int e = 0; e < 4; ++e) dit_rec<8, 1>(r + 8*e);

  const float invn = 1.f / (float)FFT_N;
  float* o0 = out + pair * (2LL * FFT_N);
  float* o1 = o0 + FFT_N;
  #pragma unroll
  for (int m = 0; m < 8; ++m){
    const int n = 4*t + (m << 10);
    v4f a, b;
    a.x = r[0*8+m].x * invn;  b.x = r[0*8+m].y * invn;
    a.y = r[1*8+m].x * invn;  b.y = r[1*8+m].y * invn;
    a.z = r[2*8+m].x * invn;  b.z = r[2*8+m].y * invn;
    a.w = r[3*8+m].x * invn;  b.w = r[3*8+m].y * invn;
    __builtin_nontemporal_store(a, reinterpret_cast<v4f*>(o0 + n));
    __builtin_nontemporal_store(b, reinterpret_cast<v4f*>(o1 + n));
  }
}

extern "C" void kernel_launch(void* const* d_in, const int* in_sizes, int n_in,
                              void* d_out, int out_size, void* d_ws, size_t ws_size,
                              hipStream_t stream) {
  const float* x = (const float*)d_in[0];
  float* out = (float*)d_out;
  const int total  = in_sizes[0];              // 64*128*8192
  const int npairs = total / (2 * FFT_N);      // 4096 row pairs
  hipLaunchKernelGGL(fourier_filter_kernel, dim3(npairs), dim3(NT), 0, stream,
                     x, out);
}

// Round 15
// 102.740 us; speedup vs baseline: 1.1574x; 1.0070x over previous
//
#include <hip/hip_runtime.h>
#include <hip/hip_fp16.h>

// FourierFilter: out = Re(IFFT(mask * FFT(x, axis=-1))), mask zeroes bins with
// |freq| < 10 Hz (kf <= 819 of 8192 @ 100 Hz). x: [64,128,8192] f32.
//
// Register-resident four-step FFT, two real rows packed per complex row.
// 256 threads x 32 complex regs. Stage grouping 3+5+5: phase-1 chains
// {4t+e+1024m} (float4 global I/O), phase-2 chains {1024(t>>5)+(t&31)+32m},
// phase-3 contiguous {32t+e} fwd FFT-32 + MASK(brev13) + inv FFT-32 fused.
// Inverse mirrors (conj pre-twiddle, DIT). 4 LDS RTs / 4 barriers.
// cmul = inline-asm VOP3P packed. LDS fp16 __half2, PHY4 pad, b128 wide ops.
//
// R14 changes (stall-shaving; R13 measured per-block latency ~21us of which
// ~8-10us is stalls — barrier convoys + load-wait + sincos chains):
// 1) Both sincos (angle 4t for P1/iP1, angle 8*(t&31) for P2/iP2) hoisted to
//    kernel top BEFORE the global loads: 2 redundant sincos deleted, latency
//    hidden under load-wait, removed from P2/iP2 barrier-to-barrier path.
// 2) P1 twiddle chains computed before load unpack (independent of data).
// 3) s_setprio(1) around P2/P3/iP2 compute clusters (blocks on a CU are
//    phase-independent -> attn-like regime where setprio measured +4-7%).
// LEDGER: R12 wave-local fence elision FAILED correctness (unexplained) —
//   do not retry without disasm. R11 persistent+prefetch lost to HW overlap.
//   R9 5-blocks/CU regressed. R6 shuffle stages regressed (VALUBusy 66%).

#define FFT_N 8192
#define NT    256
#define PHY4(i) ((i) + (((i) >> 6) << 2))

typedef float v2f __attribute__((ext_vector_type(2)));
typedef float v4f __attribute__((ext_vector_type(4)));

union H2x4 { __half2 h[4]; v4f v; };

__device__ __forceinline__ v2f cmul(v2f a, v2f b){
  v2f t, d;
  asm("v_pk_mul_f32 %0, %1, %2 op_sel:[0,0] op_sel_hi:[0,1]"
      : "=&v"(t) : "v"(a), "v"(b));
  asm("v_pk_fma_f32 %0, %1, %2, %3 op_sel:[1,1,0] op_sel_hi:[1,0,1] neg_lo:[0,1,0]"
      : "=v"(d) : "v"(a), "v"(b), "v"(t));
  return d;
}

// d * W_32^j (or conj), j in [0,16), compile-time after unroll -> constants fold.
__device__ __forceinline__ v2f mul_w32(v2f d, int j, bool cj){
  if (j == 0) return d;
  if (j == 8) return cj ? (v2f){-d.y, d.x} : (v2f){d.y, -d.x};
  const float C[16] = {1.f, 0.98078528f, 0.92387953f, 0.83146961f, 0.70710678f,
                       0.55557023f, 0.38268343f, 0.19509032f, 0.f, -0.19509032f,
                       -0.38268343f, -0.55557023f, -0.70710678f, -0.83146961f,
                       -0.92387953f, -0.98078528f};
  const float S[16] = {0.f, -0.19509032f, -0.38268343f, -0.55557023f, -0.70710678f,
                       -0.83146961f, -0.92387953f, -0.98078528f, -1.f, -0.98078528f,
                       -0.92387953f, -0.83146961f, -0.70710678f, -0.55557023f,
                       -0.38268343f, -0.19509032f};
  v2f w = {C[j], cj ? -S[j] : S[j]};
  return cmul(d, w);
}

// DIF radix-2 stages, spans L..1 over SZ regs.
template<int SZ, int L>
__device__ __forceinline__ void dif_rec(v2f* r){
  #pragma unroll
  for (int g = 0; g < SZ; g += 2*L){
    #pragma unroll
    for (int j = 0; j < L; ++j){
      v2f u = r[g+j], v = r[g+j+L];
      r[g+j]   = u + v;
      r[g+j+L] = mul_w32(u - v, j*(16/L), false);
    }
  }
  if constexpr (L > 1) dif_rec<SZ, L/2>(r);
}

// Inverse DIT radix-2 stages, spans 1..SZ/2 (conjugate twiddles), unnormalized.
template<int SZ, int L>
__device__ __forceinline__ void dit_rec(v2f* r){
  #pragma unroll
  for (int g = 0; g < SZ; g += 2*L){
    #pragma unroll
    for (int j = 0; j < L; ++j){
      v2f a = r[g+j];
      v2f b = mul_w32(r[g+j+L], j*(16/L), true);
      r[g+j]   = a + b;
      r[g+j+L] = a - b;
    }
  }
  if constexpr (2*L < SZ) dit_rec<SZ, 2*L>(r);
}

__host__ __device__ constexpr int brev5(int k){
  return ((k&1)<<4) | ((k&2)<<2) | (k&4) | ((k&8)>>2) | ((k&16)>>4);
}

// r[brev5(k)] *= w1^k (w1 given), k=1..31 (two half-chains for ILP).
__device__ __forceinline__ void twiddle_scale(v2f* r, v2f w1){
  v2f w2q = cmul(w1, w1);
  v2f w4q = cmul(w2q, w2q);
  v2f w8q = cmul(w4q, w4q);
  v2f w16 = cmul(w8q, w8q);
  v2f wa = w1;
  r[brev5(1)]  = cmul(r[brev5(1)],  wa);
  r[brev5(17)] = cmul(r[brev5(17)], cmul(w16, wa));
  #pragma unroll
  for (int k = 2; k <= 15; ++k){
    wa = cmul(wa, w1);
    r[brev5(k)]    = cmul(r[brev5(k)],    wa);
    r[brev5(k+16)] = cmul(r[brev5(k+16)], cmul(w16, wa));
  }
  r[brev5(16)] = cmul(r[brev5(16)], w16);
}

// r[brev3(k)] *= w1^k, k=1..7. brev3: 1->4, 2->2, 3->6, 4->1, 5->5, 6->3, 7->7.
__device__ __forceinline__ void tw8(v2f* r, v2f w1){
  v2f w2 = cmul(w1, w1);
  v2f w3 = cmul(w2, w1);
  v2f w4 = cmul(w2, w2);
  v2f w5 = cmul(w4, w1);
  v2f w6 = cmul(w4, w2);
  v2f w7 = cmul(w4, w3);
  r[4] = cmul(r[4], w1);
  r[2] = cmul(r[2], w2);
  r[6] = cmul(r[6], w3);
  r[1] = cmul(r[1], w4);
  r[5] = cmul(r[5], w5);
  r[3] = cmul(r[3], w6);
  r[7] = cmul(r[7], w7);
}

__global__ __launch_bounds__(NT, 2)
void fourier_filter_kernel(const float* __restrict__ x, float* __restrict__ out){
  __shared__ __half2 zs[FFT_N + (FFT_N/64)*4];   // 8704 * 4B = 34,816 B
  const int t = threadIdx.x;
  const long long pair = blockIdx.x;
  const float* r0 = x + pair * (2LL * FFT_N);
  const float* r1 = r0 + FFT_N;
  v2f r[32];

  // W_8192^1, W_8192^2 (for chain bases 4t+1, 4t+2, 4t+3)
  const v2f W1C = {0.9999997058629f, -7.669903187e-4f};
  const v2f W2C = {0.9999988234517f, -1.5339801863e-3f};

  // ---- hoisted twiddle bases (independent of loads; computed before them) ----
  v2f w0p1, w0p2;                        // W^{4t}, W_1024^{t&31} = W^{8(t&31)}
  {
    float s1, c1, s2, c2;
    __sincosf((float)(4*t) * -7.6699039394282061e-4f, &s1, &c1);
    __sincosf((float)((t & 31) << 3) * -7.6699039394282061e-4f, &s2, &c2);
    w0p1 = (v2f){c1, s1};
    w0p2 = (v2f){c2, s2};
  }
  // P1 deferred-twiddle chain bases (also load-independent)
  v2f wA = cmul(w0p1, W1C);
  v2f wB = cmul(w0p1, W2C);
  v2f wC = cmul(wA, W2C);

  // ---- fwd phase 1: 4 chains c=4t+e, FFT-8 over m (n = 4t+e+1024m) ----
  #pragma unroll
  for (int m = 0; m < 8; ++m){
    const int n = 4*t + (m << 10);
    const v4f a = *reinterpret_cast<const v4f*>(r0 + n);
    const v4f b = *reinterpret_cast<const v4f*>(r1 + n);
    r[0*8+m] = (v2f){a.x, b.x};
    r[1*8+m] = (v2f){a.y, b.y};
    r[2*8+m] = (v2f){a.z, b.z};
    r[3*8+m] = (v2f){a.w, b.w};
  }
  #pragma unroll
  for (int e = 0; e < 4; ++e) dif_rec<8, 4>(r + 8*e);
  tw8(r + 0,  w0p1);
  tw8(r + 8,  wA);
  tw8(r + 16, wB);
  tw8(r + 24, wC);
  #pragma unroll
  for (int m = 0; m < 8; ++m){
    H2x4 u;
    #pragma unroll
    for (int e = 0; e < 4; ++e)
      u.h[e] = __floats2half2_rn(r[8*e+m].x, r[8*e+m].y);
    *reinterpret_cast<v4f*>(&zs[PHY4(4*t + (m<<10))]) = u.v;   // ds_write_b128
  }
  __syncthreads();

  // ---- fwd phase 2: chains {1024(t>>5) + (t&31) + 32m}, FFT-32 ----
  const int base2 = ((t >> 5) << 10) | (t & 31);
  #pragma unroll
  for (int m = 0; m < 32; ++m){
    float2 f = __half22float2(zs[PHY4(base2 + (m<<5))]);
    r[m] = (v2f){f.x, f.y};
  }
  __builtin_amdgcn_s_setprio(1);
  dif_rec<32, 16>(r);
  twiddle_scale(r, w0p2);
  __builtin_amdgcn_s_setprio(0);
  #pragma unroll
  for (int m = 0; m < 32; ++m)
    zs[PHY4(base2 + (m<<5))] = __floats2half2_rn(r[m].x, r[m].y);
  __syncthreads();

  // ---- phase 3: contiguous FFT-32 fwd + MASK + inv, fused in regs ----
  #pragma unroll
  for (int q = 0; q < 8; ++q){
    H2x4 u;
    u.v = *reinterpret_cast<const v4f*>(&zs[PHY4((t<<5) + 4*q)]);  // ds_read_b128
    #pragma unroll
    for (int j = 0; j < 4; ++j){
      float2 f = __half22float2(u.h[j]);
      r[4*q+j] = (v2f){f.x, f.y};
    }
  }
  __builtin_amdgcn_s_setprio(1);
  dif_rec<32, 16>(r);
  #pragma unroll
  for (int e = 0; e < 32; ++e){
    const int v  = (t << 5) + e;
    const int k  = (int)(__brev((unsigned)v) >> 19);   // slot v holds bin brev13(v)
    const int kf = min(k, FFT_N - k);
    if (kf <= 819) r[e] = (v2f){0.f, 0.f};             // |freq| < 10 Hz
  }
  dit_rec<32, 1>(r);
  __builtin_amdgcn_s_setprio(0);
  #pragma unroll
  for (int q = 0; q < 8; ++q){
    H2x4 u;
    #pragma unroll
    for (int j = 0; j < 4; ++j)
      u.h[j] = __floats2half2_rn(r[4*q+j].x, r[4*q+j].y);
    *reinterpret_cast<v4f*>(&zs[PHY4((t<<5) + 4*q)]) = u.v;      // ds_write_b128
  }
  __syncthreads();

  // ---- inv phase 2: conj pre-twiddle, DIT ----
  #pragma unroll
  for (int m = 0; m < 32; ++m){
    float2 f = __half22float2(zs[PHY4(base2 + (m<<5))]);
    r[m] = (v2f){f.x, f.y};
  }
  __builtin_amdgcn_s_setprio(1);
  twiddle_scale(r, (v2f){w0p2.x, -w0p2.y});
  dit_rec<32, 1>(r);
  __builtin_amdgcn_s_setprio(0);
  #pragma unroll
  for (int m = 0; m < 32; ++m)
    zs[PHY4(base2 + (m<<5))] = __floats2half2_rn(r[m].x, r[m].y);
  __syncthreads();

  // ---- inv phase 1: conj pre-twiddle, 4 x DIT-8, vec4 store ----
  #pragma unroll
  for (int m = 0; m < 8; ++m){
    H2x4 u;
    u.v = *reinterpret_cast<const v4f*>(&zs[PHY4(4*t + (m<<10))]);  // ds_read_b128
    #pragma unroll
    for (int e = 0; e < 4; ++e){
      float2 f = __half22float2(u.h[e]);
      r[8*e+m] = (v2f){f.x, f.y};
    }
  }
  {
    v2f w0c = {w0p1.x, -w0p1.y};           // conj(W^{4t}) — reuse hoisted base
    const v2f W1Cc = {W1C.x, -W1C.y};
    const v2f W2Cc = {W2C.x, -W2C.y};
    v2f wAc = cmul(w0c, W1Cc);
    v2f wBc = cmul(w0c, W2Cc);
    v2f wCc = cmul(wAc, W2Cc);
    tw8(r + 0,  w0c);
    tw8(r + 8,  wAc);
    tw8(r + 16, wBc);
    tw8(r + 24, wCc);
  }
  #pragma unroll
  for (int e = 0; e < 4; ++e) dit_rec<8, 1>(r + 8*e);

  const float invn = 1.f / (float)FFT_N;
  float* o0 = out + pair * (2LL * FFT_N);
  float* o1 = o0 + FFT_N;
  #pragma unroll
  for (int m = 0; m < 8; ++m){
    const int n = 4*t + (m << 10);
    v4f a, b;
    a.x = r[0*8+m].x * invn;  b.x = r[0*8+m].y * invn;
    a.y = r[1*8+m].x * invn;  b.y = r[1*8+m].y * invn;
    a.z = r[2*8+m].x * invn;  b.z = r[2*8+m].y * invn;
    a.w = r[3*8+m].x * invn;  b.w = r[3*8+m].y * invn;
    __builtin_nontemporal_store(a, reinterpret_cast<v4f*>(o0 + n));
    __builtin_nontemporal_store(b, reinterpret_cast<v4f*>(o1 + n));
  }
}

extern "C" void kernel_launch(void* const* d_in, const int* in_sizes, int n_in,
                              void* d_out, int out_size, void* d_ws, size_t ws_size,
                              hipStream_t stream) {
  const float* x = (const float*)d_in[0];
  float* out = (float*)d_out;
  const int total  = in_sizes[0];              // 64*128*8192
  const int npairs = total / (2 * FFT_N);      // 4096 row pairs
  hipLaunchKernelGGL(fourier_filter_kernel, dim3(npairs), dim3(NT), 0, stream,
                     x, out);
}

// Round 16
// 102.633 us; speedup vs baseline: 1.1586x; 1.0010x over previous
//
#include <hip/hip_runtime.h>
#include <hip/hip_fp16.h>

// FourierFilter: out = Re(IFFT(mask * FFT(x, axis=-1))), mask zeroes bins with
// |freq| < 10 Hz (kf <= 819 of 8192 @ 100 Hz). x: [64,128,8192] f32.
//
// Register-resident four-step FFT, two real rows packed per complex row.
// 256 threads x 32 complex regs. Stage grouping 3+5+5: phase-1 chains
// {4t+e+1024m} (float4 global I/O), phase-2 chains {1024(t>>5)+(t&31)+32m},
// phase-3 contiguous {32t+e} fwd FFT-32 + MASK + inv FFT-32 fused.
// Inverse mirrors (conj pre-twiddle, DIT). 4 LDS RTs / 4 barriers (minimal:
// 3 phases is the fewest for N=8192 with 32 regs/thread; RTs = 2*(phases-1)).
// cmul = inline-asm VOP3P packed. LDS fp16 __half2, PHY4 pad, b128 wide ops.
// Hoisted sincos + setprio around central compute clusters (R14).
//
// R15 change: CLOSED-FORM MASK. Slot v=32t+e holds bin k=rev13(v) =
// rev5(e)*256 + rev8(t). Zero condition (k<=819 | k>=7373) by E=rev5(e):
//   E in {0,1,2,29,30,31} -> always zero  -> slots e in {0,16,8,23,15,31}
//   E=3  -> zero iff rev8(t) <= 51        -> slot e=24
//   E=28 -> zero iff rev8(t) >= 205       -> slot e=7
// (checksum: 6*256 + 52 + 51 = 1639 = #bins with kf<=819. exact.)
// Replaces 32x{brev,min,cmp,2 cndmask} (~160 ops/thread) with 8 writes;
// 6 compile-time zeros also let dit_rec's first stages fold adds.
// LEDGER: R12 fence elision broke correctness (unexplained — needs disasm).
//   R11 persistent+prefetch lost to HW inter-block overlap. R9 5-blocks/CU
//   regressed. R6 shuffle stages regressed. Radix-4: only ~5% cmul savings
//   (trivial-twiddle folding already near-optimal) — not attempted.

#define FFT_N 8192
#define NT    256
#define PHY4(i) ((i) + (((i) >> 6) << 2))

typedef float v2f __attribute__((ext_vector_type(2)));
typedef float v4f __attribute__((ext_vector_type(4)));

union H2x4 { __half2 h[4]; v4f v; };

__device__ __forceinline__ v2f cmul(v2f a, v2f b){
  v2f t, d;
  asm("v_pk_mul_f32 %0, %1, %2 op_sel:[0,0] op_sel_hi:[0,1]"
      : "=&v"(t) : "v"(a), "v"(b));
  asm("v_pk_fma_f32 %0, %1, %2, %3 op_sel:[1,1,0] op_sel_hi:[1,0,1] neg_lo:[0,1,0]"
      : "=v"(d) : "v"(a), "v"(b), "v"(t));
  return d;
}

// d * W_32^j (or conj), j in [0,16), compile-time after unroll -> constants fold.
__device__ __forceinline__ v2f mul_w32(v2f d, int j, bool cj){
  if (j == 0) return d;
  if (j == 8) return cj ? (v2f){-d.y, d.x} : (v2f){d.y, -d.x};
  const float C[16] = {1.f, 0.98078528f, 0.92387953f, 0.83146961f, 0.70710678f,
                       0.55557023f, 0.38268343f, 0.19509032f, 0.f, -0.19509032f,
                       -0.38268343f, -0.55557023f, -0.70710678f, -0.83146961f,
                       -0.92387953f, -0.98078528f};
  const float S[16] = {0.f, -0.19509032f, -0.38268343f, -0.55557023f, -0.70710678f,
                       -0.83146961f, -0.92387953f, -0.98078528f, -1.f, -0.98078528f,
                       -0.92387953f, -0.83146961f, -0.70710678f, -0.55557023f,
                       -0.38268343f, -0.19509032f};
  v2f w = {C[j], cj ? -S[j] : S[j]};
  return cmul(d, w);
}

// DIF radix-2 stages, spans L..1 over SZ regs.
template<int SZ, int L>
__device__ __forceinline__ void dif_rec(v2f* r){
  #pragma unroll
  for (int g = 0; g < SZ; g += 2*L){
    #pragma unroll
    for (int j = 0; j < L; ++j){
      v2f u = r[g+j], v = r[g+j+L];
      r[g+j]   = u + v;
      r[g+j+L] = mul_w32(u - v, j*(16/L), false);
    }
  }
  if constexpr (L > 1) dif_rec<SZ, L/2>(r);
}

// Inverse DIT radix-2 stages, spans 1..SZ/2 (conjugate twiddles), unnormalized.
template<int SZ, int L>
__device__ __forceinline__ void dit_rec(v2f* r){
  #pragma unroll
  for (int g = 0; g < SZ; g += 2*L){
    #pragma unroll
    for (int j = 0; j < L; ++j){
      v2f a = r[g+j];
      v2f b = mul_w32(r[g+j+L], j*(16/L), true);
      r[g+j]   = a + b;
      r[g+j+L] = a - b;
    }
  }
  if constexpr (2*L < SZ) dit_rec<SZ, 2*L>(r);
}

__host__ __device__ constexpr int brev5(int k){
  return ((k&1)<<4) | ((k&2)<<2) | (k&4) | ((k&8)>>2) | ((k&16)>>4);
}

// r[brev5(k)] *= w1^k (w1 given), k=1..31 (two half-chains for ILP).
__device__ __forceinline__ void twiddle_scale(v2f* r, v2f w1){
  v2f w2q = cmul(w1, w1);
  v2f w4q = cmul(w2q, w2q);
  v2f w8q = cmul(w4q, w4q);
  v2f w16 = cmul(w8q, w8q);
  v2f wa = w1;
  r[brev5(1)]  = cmul(r[brev5(1)],  wa);
  r[brev5(17)] = cmul(r[brev5(17)], cmul(w16, wa));
  #pragma unroll
  for (int k = 2; k <= 15; ++k){
    wa = cmul(wa, w1);
    r[brev5(k)]    = cmul(r[brev5(k)],    wa);
    r[brev5(k+16)] = cmul(r[brev5(k+16)], cmul(w16, wa));
  }
  r[brev5(16)] = cmul(r[brev5(16)], w16);
}

// r[brev3(k)] *= w1^k, k=1..7. brev3: 1->4, 2->2, 3->6, 4->1, 5->5, 6->3, 7->7.
__device__ __forceinline__ void tw8(v2f* r, v2f w1){
  v2f w2 = cmul(w1, w1);
  v2f w3 = cmul(w2, w1);
  v2f w4 = cmul(w2, w2);
  v2f w5 = cmul(w4, w1);
  v2f w6 = cmul(w4, w2);
  v2f w7 = cmul(w4, w3);
  r[4] = cmul(r[4], w1);
  r[2] = cmul(r[2], w2);
  r[6] = cmul(r[6], w3);
  r[1] = cmul(r[1], w4);
  r[5] = cmul(r[5], w5);
  r[3] = cmul(r[3], w6);
  r[7] = cmul(r[7], w7);
}

__global__ __launch_bounds__(NT, 2)
void fourier_filter_kernel(const float* __restrict__ x, float* __restrict__ out){
  __shared__ __half2 zs[FFT_N + (FFT_N/64)*4];   // 8704 * 4B = 34,816 B
  const int t = threadIdx.x;
  const long long pair = blockIdx.x;
  const float* r0 = x + pair * (2LL * FFT_N);
  const float* r1 = r0 + FFT_N;
  v2f r[32];

  // W_8192^1, W_8192^2 (for chain bases 4t+1, 4t+2, 4t+3)
  const v2f W1C = {0.9999997058629f, -7.669903187e-4f};
  const v2f W2C = {0.9999988234517f, -1.5339801863e-3f};

  // ---- hoisted twiddle bases (independent of loads; computed before them) ----
  v2f w0p1, w0p2;                        // W^{4t}, W_1024^{t&31} = W^{8(t&31)}
  {
    float s1, c1, s2, c2;
    __sincosf((float)(4*t) * -7.6699039394282061e-4f, &s1, &c1);
    __sincosf((float)((t & 31) << 3) * -7.6699039394282061e-4f, &s2, &c2);
    w0p1 = (v2f){c1, s1};
    w0p2 = (v2f){c2, s2};
  }
  // P1 deferred-twiddle chain bases (also load-independent)
  v2f wA = cmul(w0p1, W1C);
  v2f wB = cmul(w0p1, W2C);
  v2f wC = cmul(wA, W2C);

  // ---- fwd phase 1: 4 chains c=4t+e, FFT-8 over m (n = 4t+e+1024m) ----
  #pragma unroll
  for (int m = 0; m < 8; ++m){
    const int n = 4*t + (m << 10);
    const v4f a = *reinterpret_cast<const v4f*>(r0 + n);
    const v4f b = *reinterpret_cast<const v4f*>(r1 + n);
    r[0*8+m] = (v2f){a.x, b.x};
    r[1*8+m] = (v2f){a.y, b.y};
    r[2*8+m] = (v2f){a.z, b.z};
    r[3*8+m] = (v2f){a.w, b.w};
  }
  #pragma unroll
  for (int e = 0; e < 4; ++e) dif_rec<8, 4>(r + 8*e);
  tw8(r + 0,  w0p1);
  tw8(r + 8,  wA);
  tw8(r + 16, wB);
  tw8(r + 24, wC);
  #pragma unroll
  for (int m = 0; m < 8; ++m){
    H2x4 u;
    #pragma unroll
    for (int e = 0; e < 4; ++e)
      u.h[e] = __floats2half2_rn(r[8*e+m].x, r[8*e+m].y);
    *reinterpret_cast<v4f*>(&zs[PHY4(4*t + (m<<10))]) = u.v;   // ds_write_b128
  }
  __syncthreads();

  // ---- fwd phase 2: chains {1024(t>>5) + (t&31) + 32m}, FFT-32 ----
  const int base2 = ((t >> 5) << 10) | (t & 31);
  #pragma unroll
  for (int m = 0; m < 32; ++m){
    float2 f = __half22float2(zs[PHY4(base2 + (m<<5))]);
    r[m] = (v2f){f.x, f.y};
  }
  __builtin_amdgcn_s_setprio(1);
  dif_rec<32, 16>(r);
  twiddle_scale(r, w0p2);
  __builtin_amdgcn_s_setprio(0);
  #pragma unroll
  for (int m = 0; m < 32; ++m)
    zs[PHY4(base2 + (m<<5))] = __floats2half2_rn(r[m].x, r[m].y);
  __syncthreads();

  // ---- phase 3: contiguous FFT-32 fwd + MASK (closed form) + inv, in regs ----
  #pragma unroll
  for (int q = 0; q < 8; ++q){
    H2x4 u;
    u.v = *reinterpret_cast<const v4f*>(&zs[PHY4((t<<5) + 4*q)]);  // ds_read_b128
    #pragma unroll
    for (int j = 0; j < 4; ++j){
      float2 f = __half22float2(u.h[j]);
      r[4*q+j] = (v2f){f.x, f.y};
    }
  }
  __builtin_amdgcn_s_setprio(1);
  dif_rec<32, 16>(r);
  // Mask: slot v=32t+e holds bin k = rev5(e)*256 + rev8(t); zero iff
  // k<=819 | k>=7373.  E=rev5(e) in {0,1,2,29,30,31} -> slots {0,16,8,23,15,31}
  // always; E=3 (e=24) iff rev8(t)<=51; E=28 (e=7) iff rev8(t)>=205.
  {
    const int T = (int)(__brev((unsigned)t) >> 24);   // rev8(t)
    const v2f Z = {0.f, 0.f};
    r[0] = Z; r[8] = Z; r[15] = Z; r[16] = Z; r[23] = Z; r[31] = Z;
    if (T <= 51)  r[24] = Z;
    if (T >= 205) r[7]  = Z;
  }
  dit_rec<32, 1>(r);
  __builtin_amdgcn_s_setprio(0);
  #pragma unroll
  for (int q = 0; q < 8; ++q){
    H2x4 u;
    #pragma unroll
    for (int j = 0; j < 4; ++j)
      u.h[j] = __floats2half2_rn(r[4*q+j].x, r[4*q+j].y);
    *reinterpret_cast<v4f*>(&zs[PHY4((t<<5) + 4*q)]) = u.v;      // ds_write_b128
  }
  __syncthreads();

  // ---- inv phase 2: conj pre-twiddle, DIT ----
  #pragma unroll
  for (int m = 0; m < 32; ++m){
    float2 f = __half22float2(zs[PHY4(base2 + (m<<5))]);
    r[m] = (v2f){f.x, f.y};
  }
  __builtin_amdgcn_s_setprio(1);
  twiddle_scale(r, (v2f){w0p2.x, -w0p2.y});
  dit_rec<32, 1>(r);
  __builtin_amdgcn_s_setprio(0);
  #pragma unroll
  for (int m = 0; m < 32; ++m)
    zs[PHY4(base2 + (m<<5))] = __floats2half2_rn(r[m].x, r[m].y);
  __syncthreads();

  // ---- inv phase 1: conj pre-twiddle, 4 x DIT-8, vec4 store ----
  #pragma unroll
  for (int m = 0; m < 8; ++m){
    H2x4 u;
    u.v = *reinterpret_cast<const v4f*>(&zs[PHY4(4*t + (m<<10))]);  // ds_read_b128
    #pragma unroll
    for (int e = 0; e < 4; ++e){
      float2 f = __half22float2(u.h[e]);
      r[8*e+m] = (v2f){f.x, f.y};
    }
  }
  {
    v2f w0c = {w0p1.x, -w0p1.y};           // conj(W^{4t}) — reuse hoisted base
    const v2f W1Cc = {W1C.x, -W1C.y};
    const v2f W2Cc = {W2C.x, -W2C.y};
    v2f wAc = cmul(w0c, W1Cc);
    v2f wBc = cmul(w0c, W2Cc);
    v2f wCc = cmul(wAc, W2Cc);
    tw8(r + 0,  w0c);
    tw8(r + 8,  wAc);
    tw8(r + 16, wBc);
    tw8(r + 24, wCc);
  }
  #pragma unroll
  for (int e = 0; e < 4; ++e) dit_rec<8, 1>(r + 8*e);

  const float invn = 1.f / (float)FFT_N;
  float* o0 = out + pair * (2LL * FFT_N);
  float* o1 = o0 + FFT_N;
  #pragma unroll
  for (int m = 0; m < 8; ++m){
    const int n = 4*t + (m << 10);
    v4f a, b;
    a.x = r[0*8+m].x * invn;  b.x = r[0*8+m].y * invn;
    a.y = r[1*8+m].x * invn;  b.y = r[1*8+m].y * invn;
    a.z = r[2*8+m].x * invn;  b.z = r[2*8+m].y * invn;
    a.w = r[3*8+m].x * invn;  b.w = r[3*8+m].y * invn;
    __builtin_nontemporal_store(a, reinterpret_cast<v4f*>(o0 + n));
    __builtin_nontemporal_store(b, reinterpret_cast<v4f*>(o1 + n));
  }
}

extern "C" void kernel_launch(void* const* d_in, const int* in_sizes, int n_in,
                              void* d_out, int out_size, void* d_ws, size_t ws_size,
                              hipStream_t stream) {
  const float* x = (const float*)d_in[0];
  float* out = (float*)d_out;
  const int total  = in_sizes[0];              // 64*128*8192
  const int npairs = total / (2 * FFT_N);      // 4096 row pairs
  hipLaunchKernelGGL(fourier_filter_kernel, dim3(npairs), dim3(NT), 0, stream,
                     x, out);
}